// Round 2
// baseline (339.386 us; speedup 1.0000x reference)
//
#include <hip/hip_runtime.h>

#define C_ 96
#define H_ 512
#define W_ 96
#define HW_ 49152        // H_*W_
#define CHW_ 4718592     // C_*HW_
#define PIT 104          // LDS row pitch in f16 elements (208 B, 16B-aligned rows)
#define REG 9984         // 96*PIT elements per LDS region

typedef _Float16 f16x8 __attribute__((ext_vector_type(8)));
typedef _Float16 f16x4 __attribute__((ext_vector_type(4)));
typedef float    f32x4 __attribute__((ext_vector_type(4)));

// Prepass: qkv_w fp32 -> fp16; fold BN into per-channel scale/shift.
__global__ void prep_kernel(const float* __restrict__ wq,
                            const float* __restrict__ gamma,
                            const float* __restrict__ beta,
                            const float* __restrict__ mean,
                            const float* __restrict__ var,
                            _Float16* __restrict__ whf,
                            float* __restrict__ inv,
                            float* __restrict__ shift)
{
    int i = blockIdx.x * 256 + threadIdx.x;
    if (i < 3 * C_ * C_) whf[i] = (_Float16)wq[i];
    if (i < C_) {
        float iv = gamma[i] * rsqrtf(var[i] + 1e-5f);
        inv[i]   = iv;
        shift[i] = beta[i] - mean[i] * iv;
    }
}

// One workgroup per (b,h): BN + QKV proj + row attention + residual.
// 6 waves; wave ws owns S/O row-strip i in [16ws,16ws+16).
__global__ __launch_bounds__(384, 3) void attn_kernel(
    const float* __restrict__ x,
    const _Float16* __restrict__ wqkv,
    const float* __restrict__ bias,
    const float* __restrict__ bninv,
    const float* __restrict__ bnshift,
    float* __restrict__ out)
{
    // 3 aliased regions, 59904 B total -> 2 blocks/CU
    __shared__ _Float16 smem[3 * REG];
    _Float16* XNV = smem;           // xn[w][c] (phase 0-1), then V[c][w]
    _Float16* QP  = smem + REG;     // Q[w][c], then P[i][j] (strip-private alias)
    _Float16* Ks  = smem + 2 * REG; // K[w][c]

    const int tid  = threadIdx.x;
    const int ws   = tid >> 6;    // wave 0..5
    const int lane = tid & 63;
    const int q4   = lane >> 4;   // quad 0..3
    const int n16  = lane & 15;

    const int bh = blockIdx.x;
    const size_t base = (size_t)(bh >> 9) * CHW_ + (size_t)(bh & 511) * W_;
    const int w0 = 16 * ws + 4 * q4;

    // ---- phase 0: load x (kept in regs for residual), BN, xn -> LDS [w][c] ----
    f32x4 xr[6];
    #pragma unroll
    for (int t = 0; t < 6; ++t) {
        const int c = 16 * t + n16;
        xr[t] = *(const f32x4*)(x + base + (size_t)c * HW_ + w0);
        const float iv = bninv[c], sh = bnshift[c];
        #pragma unroll
        for (int r = 0; r < 4; ++r)
            XNV[(w0 + r) * PIT + c] = (_Float16)(xr[t][r] * iv + sh);
    }
    __syncthreads();

    // ---- phase 1: QKV = Wqkv @ XN; wave ws computes rows o in [48ws, 48ws+48) ----
    const int obase = 48 * ws;
    f32x4 acc[3][6];
    #pragma unroll
    for (int mt = 0; mt < 3; ++mt) {
        const f32x4 bb = *(const f32x4*)(bias + obase + 16 * mt + 4 * q4);
        #pragma unroll
        for (int nt = 0; nt < 6; ++nt) acc[mt][nt] = bb;
    }
    #pragma unroll
    for (int kk = 0; kk < 3; ++kk) {
        f16x8 bfr[6];
        #pragma unroll
        for (int nt = 0; nt < 6; ++nt)
            bfr[nt] = *(const f16x8*)(XNV + (16 * nt + n16) * PIT + 32 * kk + 8 * q4);
        #pragma unroll
        for (int mt = 0; mt < 3; ++mt) {
            const f16x8 afr = *(const f16x8*)(wqkv + (obase + 16 * mt + n16) * 96 + 32 * kk + 8 * q4);
            #pragma unroll
            for (int nt = 0; nt < 6; ++nt)
                acc[mt][nt] = __builtin_amdgcn_mfma_f32_16x16x32_f16(afr, bfr[nt], acc[mt][nt], 0, 0, 0);
        }
    }
    __syncthreads();   // all XN reads done before V overwrites the region

    #pragma unroll
    for (int mt = 0; mt < 3; ++mt) {
        const int o = obase + 16 * mt + 4 * q4;   // + r
        #pragma unroll
        for (int nt = 0; nt < 6; ++nt) {
            const int w = 16 * nt + n16;
            if (obase < 96) {                 // Q -> [w][c], 4 consecutive c: b64 store
                f16x4 pk;
                #pragma unroll
                for (int r = 0; r < 4; ++r) pk[r] = (_Float16)acc[mt][nt][r];
                *(f16x4*)(QP + w * PIT + o) = pk;
            } else if (obase < 192) {         // K -> [w][c]
                f16x4 pk;
                #pragma unroll
                for (int r = 0; r < 4; ++r) pk[r] = (_Float16)acc[mt][nt][r];
                *(f16x4*)(Ks + w * PIT + (o - 96)) = pk;
            } else {                          // V -> [c][w]
                #pragma unroll
                for (int r = 0; r < 4; ++r)
                    XNV[(o - 192 + r) * PIT + w] = (_Float16)acc[mt][nt][r];
            }
        }
    }
    __syncthreads();

    // ---- phase 2: S = Q^T K for row strip; softmax over j ----
    f32x4 sacc[6];
    #pragma unroll
    for (int nt = 0; nt < 6; ++nt) sacc[nt] = f32x4{0.f, 0.f, 0.f, 0.f};
    #pragma unroll
    for (int kk = 0; kk < 3; ++kk) {
        const f16x8 qa = *(const f16x8*)(QP + (16 * ws + n16) * PIT + 32 * kk + 8 * q4);
        #pragma unroll
        for (int nt = 0; nt < 6; ++nt) {
            const f16x8 kb = *(const f16x8*)(Ks + (16 * nt + n16) * PIT + 32 * kk + 8 * q4);
            sacc[nt] = __builtin_amdgcn_mfma_f32_16x16x32_f16(qa, kb, sacc[nt], 0, 0, 0);
        }
    }

    float invl[4];   // 1/rowsum for rows i = 16ws + 4*q4 + r (kept in regs)
    #pragma unroll
    for (int r = 0; r < 4; ++r) {
        float m = sacc[0][r];
        #pragma unroll
        for (int nt = 1; nt < 6; ++nt) m = fmaxf(m, sacc[nt][r]);
        #pragma unroll
        for (int d = 1; d < 16; d <<= 1) m = fmaxf(m, __shfl_xor(m, d, 64));
        float s = 0.f;
        #pragma unroll
        for (int nt = 0; nt < 6; ++nt) {
            const float e = __expf(sacc[nt][r] - m);
            sacc[nt][r] = e;
            s += e;
        }
        #pragma unroll
        for (int d = 1; d < 16; d <<= 1) s += __shfl_xor(s, d, 64);
        invl[r] = 1.f / s;
    }
    // write unnormalized P into own row strip of QP (strip-private: no barrier)
    #pragma unroll
    for (int nt = 0; nt < 6; ++nt) {
        #pragma unroll
        for (int r = 0; r < 4; ++r)
            QP[(16 * ws + 4 * q4 + r) * PIT + 16 * nt + n16] = (_Float16)sacc[nt][r];
    }

    // ---- phase 3: O^T[i,c] = sum_k P[i,k] V[c,k] ----
    f32x4 oacc[6];
    #pragma unroll
    for (int nt = 0; nt < 6; ++nt) oacc[nt] = f32x4{0.f, 0.f, 0.f, 0.f};
    #pragma unroll
    for (int kk = 0; kk < 3; ++kk) {
        const f16x8 pa = *(const f16x8*)(QP + (16 * ws + n16) * PIT + 32 * kk + 8 * q4);
        #pragma unroll
        for (int nt = 0; nt < 6; ++nt) {
            const f16x8 vb = *(const f16x8*)(XNV + (16 * nt + n16) * PIT + 32 * kk + 8 * q4);
            oacc[nt] = __builtin_amdgcn_mfma_f32_16x16x32_f16(pa, vb, oacc[nt], 0, 0, 0);
        }
    }

    // ---- epilogue: normalize by 1/l, add residual x, coalesced float4 store ----
    #pragma unroll
    for (int nt = 0; nt < 6; ++nt) {
        const int c = 16 * nt + n16;
        f32x4 o4;
        #pragma unroll
        for (int r = 0; r < 4; ++r)
            o4[r] = oacc[nt][r] * invl[r] + xr[nt][r];
        *(f32x4*)(out + base + (size_t)c * HW_ + w0) = o4;
    }
}

extern "C" void kernel_launch(void* const* d_in, const int* in_sizes, int n_in,
                              void* d_out, int out_size, void* d_ws, size_t ws_size,
                              hipStream_t stream)
{
    const float* x     = (const float*)d_in[0];
    const float* gamma = (const float*)d_in[1];
    const float* beta  = (const float*)d_in[2];
    const float* mean  = (const float*)d_in[3];
    const float* var   = (const float*)d_in[4];
    const float* qkvw  = (const float*)d_in[5];
    const float* qkvb  = (const float*)d_in[6];
    float* out = (float*)d_out;

    _Float16* whf = (_Float16*)d_ws;                       // 288*96 f16 = 55296 B
    float*  inv  = (float*)((char*)d_ws + 55296);          // 96 f32
    float*  shf  = (float*)((char*)d_ws + 55296 + 384);    // 96 f32

    prep_kernel<<<108, 256, 0, stream>>>(qkvw, gamma, beta, mean, var, whf, inv, shf);
    attn_kernel<<<4096, 384, 0, stream>>>(x, whf, qkvb, inv, shf, out);
}